// Round 2
// 732.834 us; speedup vs baseline: 1.0783x; 1.0783x over previous
//
#include <hip/hip_runtime.h>

#define HIDN 4096
#define CQD  1536
#define CKVD 512
#define NH   32
#define DH   128
#define DR   64
#define BATCH 16
#define SEQL 2048
#define HDR  (NH*DR)    // 2048
#define HDH  (NH*DH)    // 4096
#define LP1  (SEQL+1)   // 2049

// clang vector type usable with __builtin_nontemporal_*
typedef float f32x4 __attribute__((ext_vector_type(4)));

__device__ __forceinline__ f32x4 nt_load4(const float* p) {
    return __builtin_nontemporal_load((const f32x4*)p);
}
__device__ __forceinline__ void nt_store4(float* p, f32x4 v) {
    __builtin_nontemporal_store(v, (f32x4*)p);
}

// ---------------------------------------------------------------------------
// Core: C[b, col] += sum_{k in chunk} A[b,k] * W[k, col]   (1 col per thread)
// sA is k-major, b-contiguous: sA[k*16+b] -> 4x ds_read_b128 broadcast per k.
// 256-col slab per block; K-chunked across grid.y with atomic accumulate.
// ---------------------------------------------------------------------------
__device__ __forceinline__ void gemm16_col_core(
    const float* __restrict__ A, int K, int k0, int KC,
    const float* __restrict__ W, int ldW, int col,
    float* __restrict__ C, int ldC,
    float* sA, int tid) {
    for (int i = tid; i < KC * 16; i += 256) {
        int k = i >> 4, b = i & 15;
        sA[i] = A[b * K + k0 + k];
    }
    __syncthreads();
    float acc[16];
#pragma unroll
    for (int b = 0; b < 16; ++b) acc[b] = 0.f;
    const float* Wp = W + (size_t)k0 * ldW + col;
    const float4* sA4 = (const float4*)sA;
#pragma unroll 4
    for (int k = 0; k < KC; ++k) {
        float w = Wp[(size_t)k * ldW];
        float av[16];
        *(float4*)&av[0]  = sA4[k * 4 + 0];
        *(float4*)&av[4]  = sA4[k * 4 + 1];
        *(float4*)&av[8]  = sA4[k * 4 + 2];
        *(float4*)&av[12] = sA4[k * 4 + 3];
#pragma unroll
        for (int b = 0; b < 16; ++b) acc[b] += av[b] * w;
    }
#pragma unroll
    for (int b = 0; b < 16; ++b) atomicAdd(&C[b * ldC + col], acc[b]);
}

// Fused: cQ = h@W_DQ, cKV_t = h@W_DKV, kR_t = h@W_KR.  grid (16, 32), KC=128
__global__ __launch_bounds__(256) void proj_hidden(
    const float* __restrict__ hidden,
    const float* __restrict__ W_DQ, const float* __restrict__ W_DKV,
    const float* __restrict__ W_KR,
    float* __restrict__ cQ, float* __restrict__ cKV_t, float* __restrict__ kR_t) {
    const int KC = 128;
    __shared__ float sA[16 * KC];
    int nb = blockIdx.x;
    const float* W; float* C; int ld; int col0;
    if (nb < 6)      { W = W_DQ;  C = cQ;    ld = CQD;  col0 = nb * 256; }
    else if (nb < 8) { W = W_DKV; C = cKV_t; ld = CKVD; col0 = (nb - 6) * 256; }
    else             { W = W_KR;  C = kR_t;  ld = HDR;  col0 = (nb - 8) * 256; }
    gemm16_col_core(hidden, HIDN, blockIdx.y * KC, KC, W, ld,
                    col0 + threadIdx.x, C, ld, sA, threadIdx.x);
}

// Fused: qC = cQ@W_UQ_C, qR = cQ@W_UQ_R.  grid (24, 24), KC=64
__global__ __launch_bounds__(256) void proj_cq(
    const float* __restrict__ cQ,
    const float* __restrict__ W_UQ_C, const float* __restrict__ W_UQ_R,
    float* __restrict__ qC, float* __restrict__ qR) {
    const int KC = 64;
    __shared__ float sA[16 * KC];
    int nb = blockIdx.x;
    const float* W; float* C; int ld; int col0;
    if (nb < 16) { W = W_UQ_C; C = qC; ld = HDH; col0 = nb * 256; }
    else         { W = W_UQ_R; C = qR; ld = HDR; col0 = (nb - 16) * 256; }
    gemm16_col_core(cQ, CQD, blockIdx.y * KC, KC, W, ld,
                    col0 + threadIdx.x, C, ld, sA, threadIdx.x);
}

// Generic K/N-split gemm for the output projections. grid (N/256, K/KC)
template <int KC>
__global__ __launch_bounds__(256) void gemm16_gen(
    const float* __restrict__ A, const float* __restrict__ W,
    float* __restrict__ C, int K, int N) {
    __shared__ float sA[16 * KC];
    int col = blockIdx.x * 256 + threadIdx.x;
    gemm16_col_core(A, K, blockIdx.y * KC, KC, W, N, col, C, N, sA, threadIdx.x);
}

// qC_eff[b,k] = sum_c qC[b,c] * W_UK_C[k,c].  grid 512 (one k per block),
// 4 waves split c into quarters, LDS combine, direct store (no atomics).
__global__ __launch_bounds__(256) void qceff_v3(
    const float* __restrict__ qC, const float* __restrict__ WUK,
    float* __restrict__ qC_eff) {
    int k = blockIdx.x;
    int tid = threadIdx.x, wave = tid >> 6, lane = tid & 63;
    const float4* wrow = (const float4*)(WUK + (size_t)k * HDH);
    const float4* q4   = (const float4*)qC;
    float acc[16];
#pragma unroll
    for (int b = 0; b < 16; ++b) acc[b] = 0.f;
#pragma unroll
    for (int it = 0; it < 4; ++it) {
        int c4 = wave * 256 + it * 64 + lane;
        float4 w = wrow[c4];
#pragma unroll
        for (int b = 0; b < 16; ++b) {
            float4 q = q4[b * 1024 + c4];
            acc[b] += q.x * w.x + q.y * w.y + q.z * w.z + q.w * w.w;
        }
    }
    __shared__ float sRed[64];
#pragma unroll
    for (int b = 0; b < 16; ++b) {
        float v = acc[b];
#pragma unroll
        for (int off = 32; off > 0; off >>= 1) v += __shfl_down(v, off, 64);
        if (lane == 0) sRed[wave * 16 + b] = v;
    }
    __syncthreads();
    if (tid < 16)
        qC_eff[tid * CKVD + k] =
            sRed[tid] + sRed[16 + tid] + sRed[32 + tid] + sRed[48 + tid];
}

// One row of fused score + cache copy.
__device__ __forceinline__ float score_copy_row(
    int b, int l,
    const float* __restrict__ cached_cKV, const float* __restrict__ cached_kR,
    const float* __restrict__ cKV_t, const float* __restrict__ kR_t,
    float* __restrict__ out_cKV, float* __restrict__ out_kR,
    float4 qcv, float4 qrv0, float4 qrv1, int tid) {
    const float* ckv_row;
    const float* kr_row;
    if (l < SEQL) {
        ckv_row = cached_cKV + ((size_t)b * SEQL + l) * CKVD;
        kr_row  = cached_kR  + ((size_t)b * SEQL + l) * HDR;
    } else {
        ckv_row = cKV_t + b * CKVD;
        kr_row  = kR_t + b * HDR;
    }
    float* oc  = out_cKV + ((size_t)b * LP1 + l) * CKVD;
    float* okr = out_kR  + ((size_t)b * LP1 + l) * HDR;
    float acc = 0.f;
    if (tid < 128) {
        f32x4 v = nt_load4(ckv_row + tid * 4);
        *(f32x4*)(oc + tid * 4) = v;  // cached store: ctx_kernel re-reads out_cKV
        acc += v[0] * qcv.x + v[1] * qcv.y + v[2] * qcv.z + v[3] * qcv.w;
    }
    f32x4 v0 = nt_load4(kr_row + tid * 4);
    nt_store4(okr + tid * 4, v0);  // never re-read
    acc += v0[0] * qrv0.x + v0[1] * qrv0.y + v0[2] * qrv0.z + v0[3] * qrv0.w;
    f32x4 v1 = nt_load4(kr_row + (tid + 256) * 4);
    nt_store4(okr + (tid + 256) * 4, v1);
    acc += v1[0] * qrv1.x + v1[1] * qrv1.y + v1[2] * qrv1.z + v1[3] * qrv1.w;
    return acc;
}

// Fused score + cache copy, 2 rows per block.  grid (1025, 16), block 256
__global__ __launch_bounds__(256) void score_copy_kernel(
    const float* __restrict__ cached_cKV, const float* __restrict__ cached_kR,
    const float* __restrict__ cKV_t, const float* __restrict__ kR_t,
    const float* __restrict__ qC_eff, const float* __restrict__ qR,
    float* __restrict__ out_cKV, float* __restrict__ out_kR,
    float* __restrict__ scores) {
    int b = blockIdx.y;
    int tid = threadIdx.x;
    int wave = tid >> 6, lane = tid & 63;
    int r0 = blockIdx.x * 2;
    bool h1 = (r0 + 1 <= SEQL);
    const float4* qc4 = (const float4*)(qC_eff + b * CKVD);
    const float4* qr4 = (const float4*)(qR + b * HDR);
    float4 qcv = make_float4(0.f, 0.f, 0.f, 0.f);
    if (tid < 128) qcv = qc4[tid];
    float4 qrv0 = qr4[tid];
    float4 qrv1 = qr4[tid + 256];

    float acc0 = score_copy_row(b, r0, cached_cKV, cached_kR, cKV_t, kR_t,
                                out_cKV, out_kR, qcv, qrv0, qrv1, tid);
    float acc1 = 0.f;
    if (h1)
        acc1 = score_copy_row(b, r0 + 1, cached_cKV, cached_kR, cKV_t, kR_t,
                              out_cKV, out_kR, qcv, qrv0, qrv1, tid);

    __shared__ float sRed[2][4];
#pragma unroll
    for (int off = 32; off > 0; off >>= 1) acc0 += __shfl_down(acc0, off, 64);
#pragma unroll
    for (int off = 32; off > 0; off >>= 1) acc1 += __shfl_down(acc1, off, 64);
    if (lane == 0) { sRed[0][wave] = acc0; sRed[1][wave] = acc1; }
    __syncthreads();
    int nrows = h1 ? 2 : 1;
    if (tid < nrows)
        scores[b * LP1 + r0 + tid] =
            (sRed[tid][0] + sRed[tid][1] + sRed[tid][2] + sRed[tid][3]) *
            0.07216878364870323f;
}

// Per-batch softmax stats only: mz[b] = (max, 1/sum).  grid 16, block 256
__global__ __launch_bounds__(256) void msum_kernel(
    const float* __restrict__ scores, float* __restrict__ mz) {
    int b = blockIdx.x;
    int tid = threadIdx.x;
    __shared__ float red[256];
    float m = -1e30f;
    for (int i = tid; i < LP1; i += 256) m = fmaxf(m, scores[b * LP1 + i]);
    red[tid] = m; __syncthreads();
    for (int s = 128; s > 0; s >>= 1) {
        if (tid < s) red[tid] = fmaxf(red[tid], red[tid + s]);
        __syncthreads();
    }
    m = red[0]; __syncthreads();
    float sum = 0.f;
    for (int i = tid; i < LP1; i += 256) sum += __expf(scores[b * LP1 + i] - m);
    red[tid] = sum; __syncthreads();
    for (int s = 128; s > 0; s >>= 1) {
        if (tid < s) red[tid] += red[tid + s];
        __syncthreads();
    }
    if (tid == 0) { mz[b * 2] = m; mz[b * 2 + 1] = 1.0f / red[0]; }
}

// ctx[b,:] = sum_l exp(s-m)*invZ * out_cKV[b,l,:].  grid (33, 16), block 256
__global__ __launch_bounds__(256) void ctx_kernel(
    const float* __restrict__ out_cKV, const float* __restrict__ scores,
    const float* __restrict__ mz, float* __restrict__ ctx) {
    int b = blockIdx.y;
    int tid = threadIdx.x;
    int c4 = tid & 127, sub = tid >> 7;
    int l0 = blockIdx.x * 64;
    int lend = l0 + 64; if (lend > LP1) lend = LP1;
    float m = mz[b * 2], invZ = mz[b * 2 + 1];
    float4 acc = make_float4(0.f, 0.f, 0.f, 0.f);
    for (int l = l0 + sub; l < lend; l += 2) {
        float p = __expf(scores[b * LP1 + l] - m) * invZ;
        const float4* row = (const float4*)(out_cKV + ((size_t)b * LP1 + l) * CKVD);
        float4 v = row[c4];
        acc.x += p * v.x; acc.y += p * v.y; acc.z += p * v.z; acc.w += p * v.w;
    }
    float* dst = ctx + b * CKVD + c4 * 4;
    atomicAdd(dst + 0, acc.x);
    atomicAdd(dst + 1, acc.y);
    atomicAdd(dst + 2, acc.z);
    atomicAdd(dst + 3, acc.w);
}

extern "C" void kernel_launch(void* const* d_in, const int* in_sizes, int n_in,
                              void* d_out, int out_size, void* d_ws, size_t ws_size,
                              hipStream_t stream) {
    const float* hidden     = (const float*)d_in[0];
    const float* cached_cKV = (const float*)d_in[1];
    const float* cached_kR  = (const float*)d_in[2];
    const float* W_DQ   = (const float*)d_in[3];
    const float* W_DKV  = (const float*)d_in[4];
    const float* W_UQ_C = (const float*)d_in[5];
    const float* W_UQ_R = (const float*)d_in[6];
    const float* W_KR   = (const float*)d_in[7];
    const float* W_UK_C = (const float*)d_in[8];
    const float* W_UV_C = (const float*)d_in[9];
    const float* W_O    = (const float*)d_in[10];

    float* out     = (float*)d_out;                        // 16*4096
    float* out_cKV = out + BATCH * HDH;                    // 16*2049*512
    float* out_kR  = out_cKV + (size_t)BATCH * LP1 * CKVD; // 16*2049*2048

    float* ws      = (float*)d_ws;
    float* cQ      = ws;                       // 16*1536
    float* cKV_t   = cQ + BATCH * CQD;         // 16*512
    float* kR_t    = cKV_t + BATCH * CKVD;     // 16*2048
    float* qC      = kR_t + BATCH * HDR;       // 16*4096
    float* qR      = qC + BATCH * HDH;         // 16*2048
    float* qC_eff  = qR + BATCH * HDR;         // 16*512
    float* ctx     = qC_eff + BATCH * CKVD;    // 16*512
    float* tbuf    = ctx + BATCH * CKVD;       // 16*4096
    float* scores  = tbuf + BATCH * HDH;       // 16*2049
    float* mz      = scores + BATCH * LP1;     // 16*2

    // zero only the atomic-accumulated buffers (cQ..tbuf inclusive)
    size_t n_zero = (size_t)(scores - ws);
    hipMemsetAsync(d_ws, 0, n_zero * sizeof(float), stream);
    hipMemsetAsync(d_out, 0, (size_t)BATCH * HDH * sizeof(float), stream);

    dim3 blk(256);
    proj_hidden<<<dim3(16, HIDN / 128), blk, 0, stream>>>(
        hidden, W_DQ, W_DKV, W_KR, cQ, cKV_t, kR_t);
    proj_cq<<<dim3(24, CQD / 64), blk, 0, stream>>>(cQ, W_UQ_C, W_UQ_R, qC, qR);
    qceff_v3<<<dim3(CKVD), blk, 0, stream>>>(qC, W_UK_C, qC_eff);
    score_copy_kernel<<<dim3(LP1 / 2 + 1, BATCH), blk, 0, stream>>>(
        cached_cKV, cached_kR, cKV_t, kR_t, qC_eff, qR, out_cKV, out_kR, scores);
    msum_kernel<<<dim3(BATCH), blk, 0, stream>>>(scores, mz);
    ctx_kernel<<<dim3((LP1 + 63) / 64, BATCH), blk, 0, stream>>>(
        out_cKV, scores, mz, ctx);
    gemm16_gen<16><<<dim3(HDH / 256, CKVD / 16), blk, 0, stream>>>(
        ctx, W_UV_C, tbuf, CKVD, HDH);
    gemm16_gen<128><<<dim3(HIDN / 256, HDH / 128), blk, 0, stream>>>(
        tbuf, W_O, out, HDH, HIDN);
}